// Round 5
// baseline (207.154 us; speedup 1.0000x reference)
//
#include <hip/hip_runtime.h>
#include <hip/hip_bf16.h>

#define Tsz 2048
#define Csz 1024
#define Hn 16

typedef short s8v __attribute__((ext_vector_type(8)));
typedef short s4v __attribute__((ext_vector_type(4)));
typedef float f4v __attribute__((ext_vector_type(4)));

#define QSCALE (0.125f * 1.44269504088896f)  // 1/sqrt(64) * log2(e), folded into Q

__device__ __forceinline__ short bf_bits(float x) {
    __hip_bfloat16 t = __float2bfloat16(x);
    return *reinterpret_cast<short*>(&t);
}

__device__ __forceinline__ void gload_lds(const void* g, void* l) {
    __builtin_amdgcn_global_load_lds(
        (const __attribute__((address_space(1))) void*)g,
        (__attribute__((address_space(3))) void*)l, 16, 0, 0);
}

// ---------------- fused fp32 -> bf16 conversion (x + 4 weights) ----------------
__global__ void cvt5(const float* __restrict__ x, const float* __restrict__ wq,
                     const float* __restrict__ wk, const float* __restrict__ wv,
                     const float* __restrict__ wp,
                     short* __restrict__ xo, short* __restrict__ qo,
                     short* __restrict__ ko, short* __restrict__ vo,
                     short* __restrict__ po) {
    const int y = blockIdx.y;
    const float* in; short* out; int n;
    switch (y) {
        case 0: in = x;  out = xo; n = 2 * Tsz * Csz; break;
        case 1: in = wq; out = qo; n = Csz * Csz; break;
        case 2: in = wk; out = ko; n = Csz * Csz; break;
        case 3: in = wv; out = vo; n = Csz * Csz; break;
        default: in = wp; out = po; n = Csz * Csz; break;
    }
    int i = (blockIdx.x * blockDim.x + threadIdx.x) * 4;
    if (i >= n) return;
    float4 v = *(const float4*)(in + i);
    short4 o;
    o.x = bf_bits(v.x); o.y = bf_bits(v.y); o.z = bf_bits(v.z); o.w = bf_bits(v.w);
    *(short4*)(out + i) = o;
}

// ---------------- fused QKV GEMM (m97 structure) ----------------
// out[m,n] = sum_k X[m,k]*W[n,k] + b[n].  BM=BN=128, BK=32, 256 thr, wave=64x64.
// z=0: Q (bf16, *QSCALE), z=1: K (bf16), z=2: V -> Vt[(b*1024+ch)*T + t] (bf16).
__global__ __launch_bounds__(256, 3) void qkv_gemm(
    const short* __restrict__ X,
    const short* __restrict__ Wq, const short* __restrict__ Wk, const short* __restrict__ Wv,
    const float* __restrict__ bq, const float* __restrict__ bk, const float* __restrict__ bv,
    short* __restrict__ Qo, short* __restrict__ Ko, short* __restrict__ Vto)
{
    const int z = blockIdx.z;
    const short* W = (z == 0) ? Wq : (z == 1) ? Wk : Wv;
    const float* bias = (z == 0) ? bq : (z == 1) ? bk : bv;

    __shared__ __align__(16) short Ash[128 * 32];
    __shared__ __align__(16) short Bsh[128 * 32];

    const int tid = threadIdx.x, lane = tid & 63, wave = tid >> 6;
    const int ln = lane & 15, hi = lane >> 4;
    const int m0 = blockIdx.x * 128, n0 = blockIdx.y * 128;
    const int wm = (wave >> 1) * 64, wn = (wave & 1) * 64;

    const short* Ag = X + (size_t)(m0 + (tid >> 2)) * Csz + (tid & 3) * 8;
    const short* Bg = W + (size_t)(n0 + (tid >> 2)) * Csz + (tid & 3) * 8;

    f4v acc[4][4];
    #pragma unroll
    for (int mt = 0; mt < 4; mt++)
        #pragma unroll
        for (int nt = 0; nt < 4; nt++)
            #pragma unroll
            for (int i = 0; i < 4; i++) acc[mt][nt][i] = 0.f;

    for (int k0 = 0; k0 < Csz; k0 += 32) {
        __syncthreads();
        gload_lds(Ag + k0, Ash + tid * 8);
        gload_lds(Ag + k0 + (size_t)64 * Csz, Ash + 2048 + tid * 8);
        gload_lds(Bg + k0, Bsh + tid * 8);
        gload_lds(Bg + k0 + (size_t)64 * Csz, Bsh + 2048 + tid * 8);
        __syncthreads();

        s8v af[4], bfr[4];
        #pragma unroll
        for (int mt = 0; mt < 4; mt++)
            af[mt] = *(const s8v*)(Ash + (wm + mt * 16 + ln) * 32 + hi * 8);
        #pragma unroll
        for (int nt = 0; nt < 4; nt++)
            bfr[nt] = *(const s8v*)(Bsh + (wn + nt * 16 + ln) * 32 + hi * 8);
        #pragma unroll
        for (int mt = 0; mt < 4; mt++)
            #pragma unroll
            for (int nt = 0; nt < 4; nt++)
                acc[mt][nt] = __builtin_amdgcn_mfma_f32_16x16x32_bf16(af[mt], bfr[nt], acc[mt][nt], 0, 0, 0);
    }

    const float scale = (z == 0) ? QSCALE : 1.0f;
    short* out = (z == 0) ? Qo : Ko;

    #pragma unroll
    for (int nt = 0; nt < 4; nt++) {
        const int col = n0 + wn + nt * 16 + ln;
        const float bvv = bias[col];
        #pragma unroll
        for (int mt = 0; mt < 4; mt++) {
            const int row0 = m0 + wm + mt * 16 + hi * 4;
            if (z == 2) {
                const int b = row0 >> 11, t = row0 & 2047;
                s4v pk;
                #pragma unroll
                for (int i = 0; i < 4; i++) pk[i] = bf_bits(acc[mt][nt][i] + bvv);
                *(s4v*)(Vto + (size_t)(b * 1024 + col) * Tsz + t) = pk;
            } else {
                #pragma unroll
                for (int i = 0; i < 4; i++)
                    out[(size_t)(row0 + i) * Csz + col] = bf_bits((acc[mt][nt][i] + bvv) * scale);
            }
        }
    }
}

// ---------------- output projection GEMM (f32 out), 128x64 tiles ----------------
__global__ __launch_bounds__(256, 2) void proj_gemm(
    const short* __restrict__ A, const short* __restrict__ W,
    const float* __restrict__ bias, float* __restrict__ out)
{
    __shared__ __align__(16) short Ash[128 * 32];
    __shared__ __align__(16) short Bsh[64 * 32];

    const int tid = threadIdx.x, lane = tid & 63, wave = tid >> 6;
    const int ln = lane & 15, hi = lane >> 4;
    const int m0 = blockIdx.x * 128, n0 = blockIdx.y * 64;
    const int wm = (wave >> 1) * 64, wn = (wave & 1) * 32;

    const short* Ag = A + (size_t)(m0 + (tid >> 2)) * Csz + (tid & 3) * 8;
    const short* Bg = W + (size_t)(n0 + (tid >> 2)) * Csz + (tid & 3) * 8;

    f4v acc[4][2];
    #pragma unroll
    for (int mt = 0; mt < 4; mt++)
        #pragma unroll
        for (int nt = 0; nt < 2; nt++)
            #pragma unroll
            for (int i = 0; i < 4; i++) acc[mt][nt][i] = 0.f;

    for (int k0 = 0; k0 < Csz; k0 += 32) {
        __syncthreads();
        gload_lds(Ag + k0, Ash + tid * 8);
        gload_lds(Ag + k0 + (size_t)64 * Csz, Ash + 2048 + tid * 8);
        gload_lds(Bg + k0, Bsh + tid * 8);
        __syncthreads();

        s8v af[4], bfr[2];
        #pragma unroll
        for (int mt = 0; mt < 4; mt++)
            af[mt] = *(const s8v*)(Ash + (wm + mt * 16 + ln) * 32 + hi * 8);
        #pragma unroll
        for (int nt = 0; nt < 2; nt++)
            bfr[nt] = *(const s8v*)(Bsh + (wn + nt * 16 + ln) * 32 + hi * 8);
        #pragma unroll
        for (int mt = 0; mt < 4; mt++)
            #pragma unroll
            for (int nt = 0; nt < 2; nt++)
                acc[mt][nt] = __builtin_amdgcn_mfma_f32_16x16x32_bf16(af[mt], bfr[nt], acc[mt][nt], 0, 0, 0);
    }

    #pragma unroll
    for (int nt = 0; nt < 2; nt++) {
        const int col = n0 + wn + nt * 16 + ln;
        const float bvv = bias[col];
        #pragma unroll
        for (int mt = 0; mt < 4; mt++)
            #pragma unroll
            for (int i = 0; i < 4; i++)
                out[(size_t)(m0 + wm + mt * 16 + hi * 4 + i) * Csz + col] = acc[mt][nt][i] + bvv;
    }
}

// ---------------- Flash attention v5 (unpaired, prefetch-pipelined) ----------------
// Q,K: [B,T,C] bf16; Vt: [B*H*64, T] bf16; Y: [B,T,C] bf16.
// St = K*Q^T, O^T = Vt*P^T; P^T re-laid out via wave-private LDS.
// Grid (32, 32): x = q-tile (heavy first), y = bh. Block: 4 waves, 64 q rows.
__global__ __launch_bounds__(256, 4) void attn5(
    const short* __restrict__ Q, const short* __restrict__ Kg,
    const short* __restrict__ Vt, short* __restrict__ Y)
{
    __shared__ __align__(16) short Ksh[64 * 72];    // [key][d], pitch 72
    __shared__ __align__(16) short Vsh[64 * 72];    // [d][key], pitch 72
    __shared__ __align__(16) short Psh[4][16 * 72]; // per-wave Pq[q][key]

    const int tid = threadIdx.x, lane = tid & 63, wave = tid >> 6;
    const int ln = lane & 15, hi = lane >> 4;
    const int qt = 31 - (int)blockIdx.x;     // heavy tiles first
    const int q0 = qt * 64;
    const int bh = blockIdx.y;
    const size_t base = (size_t)(bh >> 4) * Tsz * Csz + (size_t)(bh & 15) * 64;
    const size_t vtbase = (size_t)bh * 64 * Tsz;
    const int qrel = wave * 16 + ln;         // within-tile q row (MFMA n-col)
    short* Pq = Psh[wave];

    s8v qf[2];
    #pragma unroll
    for (int kk = 0; kk < 2; kk++)
        qf[kk] = *(const s8v*)(Q + base + (size_t)(q0 + qrel) * Csz + kk * 32 + hi * 8);

    f4v o[4], lacc;
    #pragma unroll
    for (int i = 0; i < 4; i++) lacc[i] = 0.f;
    #pragma unroll
    for (int dt = 0; dt < 4; dt++)
        #pragma unroll
        for (int i = 0; i < 4; i++) o[dt][i] = 0.f;

    s8v ones;
    #pragma unroll
    for (int j = 0; j < 8; j++) ones[j] = (short)0x3F80;  // bf16 1.0

    const int sr = tid >> 2, sc = (tid & 3) * 16;
    const short* Kp = Kg + base + (size_t)sr * Csz + sc;
    const short* Vp = Vt + vtbase + (size_t)sr * Tsz + sc;
    short* KshW = Ksh + sr * 72 + sc;
    short* VshW = Vsh + sr * 72 + sc;

    const int nkb = qt + 1;
    // prefetch kb=0
    s8v ka  = *(const s8v*)(Kp);
    s8v kb2 = *(const s8v*)(Kp + 8);
    s8v va  = *(const s8v*)(Vp);
    s8v vb2 = *(const s8v*)(Vp + 8);

    for (int kb = 0; kb < nkb; kb++) {
        __syncthreads();
        *(s8v*)(KshW) = ka; *(s8v*)(KshW + 8) = kb2;
        *(s8v*)(VshW) = va; *(s8v*)(VshW + 8) = vb2;
        __syncthreads();

        // prefetch next tile (overlaps fragment reads + MFMA below)
        const int knx = (kb + 1 < nkb) ? (kb + 1) * 64 : kb * 64;
        ka  = *(const s8v*)(Kp + (size_t)knx * Csz);
        kb2 = *(const s8v*)(Kp + (size_t)knx * Csz + 8);
        va  = *(const s8v*)(Vp + knx);
        vb2 = *(const s8v*)(Vp + knx + 8);

        s8v kf[2][4], vf[2][4];
        #pragma unroll
        for (int nt = 0; nt < 4; nt++)
            #pragma unroll
            for (int kk = 0; kk < 2; kk++) {
                kf[kk][nt] = *(const s8v*)(Ksh + (nt * 16 + ln) * 72 + kk * 32 + hi * 8);
                vf[kk][nt] = *(const s8v*)(Vsh + (nt * 16 + ln) * 72 + kk * 32 + hi * 8);
            }

        const bool dg = (kb == qt);          // diagonal block

        f4v s[4];
        #pragma unroll
        for (int nt = 0; nt < 4; nt++) {
            #pragma unroll
            for (int i = 0; i < 4; i++) s[nt][i] = 0.f;
            s[nt] = __builtin_amdgcn_mfma_f32_16x16x32_bf16(kf[0][nt], qf[0], s[nt], 0, 0, 0);
            s[nt] = __builtin_amdgcn_mfma_f32_16x16x32_bf16(kf[1][nt], qf[1], s[nt], 0, 0, 0);
        }

        // P^T write: lane holds keys nt*16+hi*4+{0..3} for q=ln
        #pragma unroll
        for (int nt = 0; nt < 4; nt++) {
            float pv[4];
            #pragma unroll
            for (int i = 0; i < 4; i++) pv[i] = exp2f(s[nt][i]);
            if (dg) {
                const int kr = nt * 16 + hi * 4;
                #pragma unroll
                for (int i = 0; i < 4; i++)
                    if (kr + i > qrel) pv[i] = 0.f;
            }
            s4v w;
            #pragma unroll
            for (int i = 0; i < 4; i++) w[i] = bf_bits(pv[i]);
            *(s4v*)(Pq + ln * 72 + nt * 16 + hi * 4) = w;  // ds_write_b64
        }
        // B-frag read: keys kk*32+hi*8+{0..7} for q=ln
        const s8v pb0 = *(const s8v*)(Pq + ln * 72 + hi * 8);
        const s8v pb1 = *(const s8v*)(Pq + ln * 72 + 32 + hi * 8);

        #pragma unroll
        for (int dt = 0; dt < 4; dt++) {
            o[dt] = __builtin_amdgcn_mfma_f32_16x16x32_bf16(vf[0][dt], pb0, o[dt], 0, 0, 0);
            o[dt] = __builtin_amdgcn_mfma_f32_16x16x32_bf16(vf[1][dt], pb1, o[dt], 0, 0, 0);
        }
        lacc = __builtin_amdgcn_mfma_f32_16x16x32_bf16(ones, pb0, lacc, 0, 0, 0);
        lacc = __builtin_amdgcn_mfma_f32_16x16x32_bf16(ones, pb1, lacc, 0, 0, 0);
    }

    const float inv = 1.0f / lacc[0];
    const int qrow = q0 + qrel;
    #pragma unroll
    for (int dt = 0; dt < 4; dt++) {
        s4v w;
        #pragma unroll
        for (int i = 0; i < 4; i++) w[i] = bf_bits(o[dt][i] * inv);
        *(s4v*)(Y + base + (size_t)qrow * Csz + dt * 16 + hi * 4) = w;
    }
}

extern "C" void kernel_launch(void* const* d_in, const int* in_sizes, int n_in,
                              void* d_out, int out_size, void* d_ws, size_t ws_size,
                              hipStream_t stream) {
    const float* x  = (const float*)d_in[0];
    const float* Wq = (const float*)d_in[1];
    const float* bq = (const float*)d_in[2];
    const float* Wk = (const float*)d_in[3];
    const float* bk = (const float*)d_in[4];
    const float* Wv = (const float*)d_in[5];
    const float* bv = (const float*)d_in[6];
    const float* Wp = (const float*)d_in[7];
    const float* bp = (const float*)d_in[8];

    char* ws = (char*)d_ws;
    short* Xb  = (short*)(ws);                 // 8 MB
    short* Wqb = (short*)(ws + (8u  << 20));   // 2 MB each
    short* Wkb = (short*)(ws + (10u << 20));
    short* Wvb = (short*)(ws + (12u << 20));
    short* Wpb = (short*)(ws + (14u << 20));
    short* Qb  = (short*)(ws + (16u << 20));   // 8 MB each
    short* Kb  = (short*)(ws + (24u << 20));
    short* Vtb = (short*)(ws + (32u << 20));   // V transposed per head [B*H*64, T]
    short* Yb  = (short*)(ws + (40u << 20));

    hipLaunchKernelGGL(cvt5, dim3(4096, 5), dim3(256), 0, stream,
                       x, Wq, Wk, Wv, Wp, Xb, Wqb, Wkb, Wvb, Wpb);

    hipLaunchKernelGGL(qkv_gemm, dim3(32, 8, 3), dim3(256), 0, stream,
                       Xb, Wqb, Wkb, Wvb, bq, bk, bv, Qb, Kb, Vtb);

    hipLaunchKernelGGL(attn5, dim3(32, 32), dim3(256), 0, stream, Qb, Kb, Vtb, Yb);

    hipLaunchKernelGGL(proj_gemm, dim3(32, 16), dim3(256), 0, stream, Yb, Wpb, bp, (float*)d_out);
}

// Round 6
// 192.283 us; speedup vs baseline: 1.0773x; 1.0773x over previous
//
#include <hip/hip_runtime.h>
#include <hip/hip_bf16.h>

#define Tsz 2048
#define Csz 1024
#define Hn 16

typedef short s8v __attribute__((ext_vector_type(8)));
typedef short s4v __attribute__((ext_vector_type(4)));
typedef float f4v __attribute__((ext_vector_type(4)));

#define QSCALE (0.125f * 1.44269504088896f)  // 1/sqrt(64) * log2(e), folded into Q

__device__ __forceinline__ short bf_bits(float x) {
    __hip_bfloat16 t = __float2bfloat16(x);
    return *reinterpret_cast<short*>(&t);
}

__device__ __forceinline__ void gload_lds(const void* g, void* l) {
    __builtin_amdgcn_global_load_lds(
        (const __attribute__((address_space(1))) void*)g,
        (__attribute__((address_space(3))) void*)l, 16, 0, 0);
}

// ---------------- fused fp32 -> bf16 conversion (x + 4 weights) ----------------
__global__ void cvt5(const float* __restrict__ x, const float* __restrict__ wq,
                     const float* __restrict__ wk, const float* __restrict__ wv,
                     const float* __restrict__ wp,
                     short* __restrict__ xo, short* __restrict__ qo,
                     short* __restrict__ ko, short* __restrict__ vo,
                     short* __restrict__ po) {
    const int y = blockIdx.y;
    const float* in; short* out; int n;
    switch (y) {
        case 0: in = x;  out = xo; n = 2 * Tsz * Csz; break;
        case 1: in = wq; out = qo; n = Csz * Csz; break;
        case 2: in = wk; out = ko; n = Csz * Csz; break;
        case 3: in = wv; out = vo; n = Csz * Csz; break;
        default: in = wp; out = po; n = Csz * Csz; break;
    }
    int i = (blockIdx.x * blockDim.x + threadIdx.x) * 4;
    if (i >= n) return;
    float4 v = *(const float4*)(in + i);
    short4 o;
    o.x = bf_bits(v.x); o.y = bf_bits(v.y); o.z = bf_bits(v.z); o.w = bf_bits(v.w);
    *(short4*)(out + i) = o;
}

// ---------------- fused QKV GEMM (m97 structure) ----------------
// out[m,n] = sum_k X[m,k]*W[n,k] + b[n].  BM=BN=128, BK=32, 256 thr, wave=64x64.
// z=0: Q (bf16, *QSCALE), z=1: K (bf16), z=2: V -> Vt[(b*1024+ch)*T + t] (bf16,
// via LDS-transpose epilogue with coalesced stores).
__global__ __launch_bounds__(256, 3) void qkv_gemm(
    const short* __restrict__ X,
    const short* __restrict__ Wq, const short* __restrict__ Wk, const short* __restrict__ Wv,
    const float* __restrict__ bq, const float* __restrict__ bk, const float* __restrict__ bv,
    short* __restrict__ Qo, short* __restrict__ Ko, short* __restrict__ Vto)
{
    const int z = blockIdx.z;
    const short* W = (z == 0) ? Wq : (z == 1) ? Wk : Wv;
    const float* bias = (z == 0) ? bq : (z == 1) ? bk : bv;

    __shared__ __align__(16) short Ash[128 * 32];
    __shared__ __align__(16) short Bsh[128 * 32];
    __shared__ __align__(16) short TR[64 * 72];   // transpose staging (z==2 epilogue)

    const int tid = threadIdx.x, lane = tid & 63, wave = tid >> 6;
    const int ln = lane & 15, hi = lane >> 4;
    const int m0 = blockIdx.x * 128, n0 = blockIdx.y * 128;
    const int wm = (wave >> 1) * 64, wn = (wave & 1) * 64;

    const short* Ag = X + (size_t)(m0 + (tid >> 2)) * Csz + (tid & 3) * 8;
    const short* Bg = W + (size_t)(n0 + (tid >> 2)) * Csz + (tid & 3) * 8;

    f4v acc[4][4];
    #pragma unroll
    for (int mt = 0; mt < 4; mt++)
        #pragma unroll
        for (int nt = 0; nt < 4; nt++)
            #pragma unroll
            for (int i = 0; i < 4; i++) acc[mt][nt][i] = 0.f;

    for (int k0 = 0; k0 < Csz; k0 += 32) {
        __syncthreads();
        gload_lds(Ag + k0, Ash + tid * 8);
        gload_lds(Ag + k0 + (size_t)64 * Csz, Ash + 2048 + tid * 8);
        gload_lds(Bg + k0, Bsh + tid * 8);
        gload_lds(Bg + k0 + (size_t)64 * Csz, Bsh + 2048 + tid * 8);
        __syncthreads();

        s8v af[4], bfr[4];
        #pragma unroll
        for (int mt = 0; mt < 4; mt++)
            af[mt] = *(const s8v*)(Ash + (wm + mt * 16 + ln) * 32 + hi * 8);
        #pragma unroll
        for (int nt = 0; nt < 4; nt++)
            bfr[nt] = *(const s8v*)(Bsh + (wn + nt * 16 + ln) * 32 + hi * 8);
        #pragma unroll
        for (int mt = 0; mt < 4; mt++)
            #pragma unroll
            for (int nt = 0; nt < 4; nt++)
                acc[mt][nt] = __builtin_amdgcn_mfma_f32_16x16x32_bf16(af[mt], bfr[nt], acc[mt][nt], 0, 0, 0);
    }

    if (z == 2) {
        // LDS-transpose epilogue: 4 passes, each pass covers (m-half, n-half).
        const int b = m0 >> 11, t0 = m0 & 2047;
        float bvv[4];
        #pragma unroll
        for (int nt = 0; nt < 4; nt++) bvv[nt] = bias[n0 + wn + nt * 16 + ln];
        #pragma unroll
        for (int ph = 0; ph < 4; ph++) {
            const int mh = ph >> 1, nh = ph & 1;
            __syncthreads();
            if ((wave >> 1) == mh && (wave & 1) == nh) {
                #pragma unroll
                for (int mt = 0; mt < 4; mt++)
                    #pragma unroll
                    for (int nt = 0; nt < 4; nt++) {
                        s4v pk;
                        #pragma unroll
                        for (int i = 0; i < 4; i++) pk[i] = bf_bits(acc[mt][nt][i] + bvv[nt]);
                        *(s4v*)(TR + (nt * 16 + ln) * 72 + mt * 16 + hi * 4) = pk;
                    }
            }
            __syncthreads();
            const int chl = tid >> 2, seg = tid & 3;   // 64 ch rows x 4 t-segments
            const s8v r0 = *(const s8v*)(TR + chl * 72 + seg * 16);
            const s8v r1 = *(const s8v*)(TR + chl * 72 + seg * 16 + 8);
            short* dst = Vto + (size_t)(b * 1024 + n0 + nh * 64 + chl) * Tsz + t0 + mh * 64 + seg * 16;
            *(s8v*)(dst) = r0;
            *(s8v*)(dst + 8) = r1;
        }
        return;
    }

    const float scale = (z == 0) ? QSCALE : 1.0f;
    short* out = (z == 0) ? Qo : Ko;

    #pragma unroll
    for (int nt = 0; nt < 4; nt++) {
        const int col = n0 + wn + nt * 16 + ln;
        const float bvv = bias[col];
        #pragma unroll
        for (int mt = 0; mt < 4; mt++) {
            const int row0 = m0 + wm + mt * 16 + hi * 4;
            #pragma unroll
            for (int i = 0; i < 4; i++)
                out[(size_t)(row0 + i) * Csz + col] = bf_bits((acc[mt][nt][i] + bvv) * scale);
        }
    }
}

// ---------------- output projection GEMM (f32 out), 128x64 tiles ----------------
__global__ __launch_bounds__(256, 2) void proj_gemm(
    const short* __restrict__ A, const short* __restrict__ W,
    const float* __restrict__ bias, float* __restrict__ out)
{
    __shared__ __align__(16) short Ash[128 * 32];
    __shared__ __align__(16) short Bsh[64 * 32];

    const int tid = threadIdx.x, lane = tid & 63, wave = tid >> 6;
    const int ln = lane & 15, hi = lane >> 4;
    const int m0 = blockIdx.x * 128, n0 = blockIdx.y * 64;
    const int wm = (wave >> 1) * 64, wn = (wave & 1) * 32;

    const short* Ag = A + (size_t)(m0 + (tid >> 2)) * Csz + (tid & 3) * 8;
    const short* Bg = W + (size_t)(n0 + (tid >> 2)) * Csz + (tid & 3) * 8;

    f4v acc[4][2];
    #pragma unroll
    for (int mt = 0; mt < 4; mt++)
        #pragma unroll
        for (int nt = 0; nt < 2; nt++)
            #pragma unroll
            for (int i = 0; i < 4; i++) acc[mt][nt][i] = 0.f;

    for (int k0 = 0; k0 < Csz; k0 += 32) {
        __syncthreads();
        gload_lds(Ag + k0, Ash + tid * 8);
        gload_lds(Ag + k0 + (size_t)64 * Csz, Ash + 2048 + tid * 8);
        gload_lds(Bg + k0, Bsh + tid * 8);
        __syncthreads();

        s8v af[4], bfr[2];
        #pragma unroll
        for (int mt = 0; mt < 4; mt++)
            af[mt] = *(const s8v*)(Ash + (wm + mt * 16 + ln) * 32 + hi * 8);
        #pragma unroll
        for (int nt = 0; nt < 2; nt++)
            bfr[nt] = *(const s8v*)(Bsh + (wn + nt * 16 + ln) * 32 + hi * 8);
        #pragma unroll
        for (int mt = 0; mt < 4; mt++)
            #pragma unroll
            for (int nt = 0; nt < 2; nt++)
                acc[mt][nt] = __builtin_amdgcn_mfma_f32_16x16x32_bf16(af[mt], bfr[nt], acc[mt][nt], 0, 0, 0);
    }

    #pragma unroll
    for (int nt = 0; nt < 2; nt++) {
        const int col = n0 + wn + nt * 16 + ln;
        const float bvv = bias[col];
        #pragma unroll
        for (int mt = 0; mt < 4; mt++)
            #pragma unroll
            for (int i = 0; i < 4; i++)
                out[(size_t)(m0 + wm + mt * 16 + hi * 4 + i) * Csz + col] = acc[mt][nt][i] + bvv;
    }
}

// ---------------- Flash attention v6 (paired attn4 + prefetch + VALU l-sum) ----------------
// Q,K: [B,T,C] bf16; Vt: [B*H*64, T] bf16; Y: [B,T,C] bf16.
// St = K*Q^T, O^T = Vt*P^T; P^T re-laid out via wave-private LDS.
// Block: 4 waves; handles q-tiles p and 31-p (64 rows each); wave owns 16 rows of both.
__global__ __launch_bounds__(256, 2) void attn6(
    const short* __restrict__ Q, const short* __restrict__ Kg,
    const short* __restrict__ Vt, short* __restrict__ Y)
{
    __shared__ __align__(16) short Ksh[64 * 72];    // [key][d], pitch 72
    __shared__ __align__(16) short Vsh[64 * 72];    // [d][key], pitch 72
    __shared__ __align__(16) short Psh[4][16 * 72]; // per-wave Pq[q][key]

    const int tid = threadIdx.x, lane = tid & 63, wave = tid >> 6;
    const int ln = lane & 15, hi = lane >> 4;
    const int p = blockIdx.x;                // pair 0..15
    const int qts[2] = { p, 31 - p };        // light, heavy 64-row q-tiles
    const int bh = blockIdx.y;
    const size_t base = (size_t)(bh >> 4) * Tsz * Csz + (size_t)(bh & 15) * 64;
    const size_t vtbase = (size_t)bh * 64 * Tsz;
    const int qrel = wave * 16 + ln;         // within-tile q row (MFMA n-col)
    short* Pq = Psh[wave];

    s8v qf[2][2];
    #pragma unroll
    for (int t = 0; t < 2; t++)
        #pragma unroll
        for (int kk = 0; kk < 2; kk++)
            qf[t][kk] = *(const s8v*)(Q + base + (size_t)(qts[t] * 64 + qrel) * Csz + kk * 32 + hi * 8);

    f4v o[2][4];
    float lsum[2] = {0.f, 0.f};
    #pragma unroll
    for (int t = 0; t < 2; t++)
        #pragma unroll
        for (int dt = 0; dt < 4; dt++)
            #pragma unroll
            for (int i = 0; i < 4; i++) o[t][dt][i] = 0.f;

    const int sr = tid >> 2, sc = (tid & 3) * 16;
    const short* Kp = Kg + base + (size_t)sr * Csz + sc;
    const short* Vp = Vt + vtbase + (size_t)sr * Tsz + sc;
    short* KshW = Ksh + sr * 72 + sc;
    short* VshW = Vsh + sr * 72 + sc;

    const int nkb = qts[1] + 1;
    // prefetch kb=0
    s8v ka  = *(const s8v*)(Kp);
    s8v kb2 = *(const s8v*)(Kp + 8);
    s8v va  = *(const s8v*)(Vp);
    s8v vb2 = *(const s8v*)(Vp + 8);

    for (int kb = 0; kb < nkb; kb++) {
        __syncthreads();
        *(s8v*)(KshW) = ka; *(s8v*)(KshW + 8) = kb2;
        *(s8v*)(VshW) = va; *(s8v*)(VshW + 8) = vb2;
        __syncthreads();

        // prefetch next K/V tile (latency overlaps fragment reads + MFMA below)
        const int knx = (kb + 1 < nkb) ? (kb + 1) * 64 : kb * 64;
        ka  = *(const s8v*)(Kp + (size_t)knx * Csz);
        kb2 = *(const s8v*)(Kp + (size_t)knx * Csz + 8);
        va  = *(const s8v*)(Vp + knx);
        vb2 = *(const s8v*)(Vp + knx + 8);

        s8v kf[2][4], vf[2][4];
        #pragma unroll
        for (int nt = 0; nt < 4; nt++)
            #pragma unroll
            for (int kk = 0; kk < 2; kk++) {
                kf[kk][nt] = *(const s8v*)(Ksh + (nt * 16 + ln) * 72 + kk * 32 + hi * 8);
                vf[kk][nt] = *(const s8v*)(Vsh + (nt * 16 + ln) * 72 + kk * 32 + hi * 8);
            }

        #pragma unroll
        for (int t = 0; t < 2; t++) {
            if (t == 0 && kb > qts[0]) continue;   // light tile done (uniform branch)
            const bool dg = (kb == qts[t]);        // diagonal block for this tile

            f4v s[4];
            #pragma unroll
            for (int nt = 0; nt < 4; nt++) {
                #pragma unroll
                for (int i = 0; i < 4; i++) s[nt][i] = 0.f;
                s[nt] = __builtin_amdgcn_mfma_f32_16x16x32_bf16(kf[0][nt], qf[t][0], s[nt], 0, 0, 0);
                s[nt] = __builtin_amdgcn_mfma_f32_16x16x32_bf16(kf[1][nt], qf[t][1], s[nt], 0, 0, 0);
            }

            // P^T write: lane holds keys nt*16+hi*4+{0..3} for q=ln; accumulate l in VALU
            #pragma unroll
            for (int nt = 0; nt < 4; nt++) {
                float pv[4];
                #pragma unroll
                for (int i = 0; i < 4; i++) pv[i] = exp2f(s[nt][i]);
                if (dg) {
                    const int kr = nt * 16 + hi * 4;
                    #pragma unroll
                    for (int i = 0; i < 4; i++)
                        if (kr + i > qrel) pv[i] = 0.f;
                }
                lsum[t] += (pv[0] + pv[1]) + (pv[2] + pv[3]);
                s4v w;
                #pragma unroll
                for (int i = 0; i < 4; i++) w[i] = bf_bits(pv[i]);
                *(s4v*)(Pq + ln * 72 + nt * 16 + hi * 4) = w;  // ds_write_b64
            }
            // B-frag read: keys kk*32+hi*8+{0..7} for q=ln
            const s8v pb0 = *(const s8v*)(Pq + ln * 72 + hi * 8);
            const s8v pb1 = *(const s8v*)(Pq + ln * 72 + 32 + hi * 8);

            #pragma unroll
            for (int dt = 0; dt < 4; dt++) {
                o[t][dt] = __builtin_amdgcn_mfma_f32_16x16x32_bf16(vf[0][dt], pb0, o[t][dt], 0, 0, 0);
                o[t][dt] = __builtin_amdgcn_mfma_f32_16x16x32_bf16(vf[1][dt], pb1, o[t][dt], 0, 0, 0);
            }
        }
    }

    // l = sum over all keys for q=ln: reduce lsum across the 4 hi-groups (lanes ln+16k)
    #pragma unroll
    for (int t = 0; t < 2; t++) {
        float l = lsum[t];
        l += __shfl_xor(l, 16);
        l += __shfl_xor(l, 32);
        const float inv = 1.0f / l;
        const int qrow = qts[t] * 64 + qrel;
        #pragma unroll
        for (int dt = 0; dt < 4; dt++) {
            s4v w;
            #pragma unroll
            for (int i = 0; i < 4; i++) w[i] = bf_bits(o[t][dt][i] * inv);
            *(s4v*)(Y + base + (size_t)qrow * Csz + dt * 16 + hi * 4) = w;
        }
    }
}

extern "C" void kernel_launch(void* const* d_in, const int* in_sizes, int n_in,
                              void* d_out, int out_size, void* d_ws, size_t ws_size,
                              hipStream_t stream) {
    const float* x  = (const float*)d_in[0];
    const float* Wq = (const float*)d_in[1];
    const float* bq = (const float*)d_in[2];
    const float* Wk = (const float*)d_in[3];
    const float* bk = (const float*)d_in[4];
    const float* Wv = (const float*)d_in[5];
    const float* bv = (const float*)d_in[6];
    const float* Wp = (const float*)d_in[7];
    const float* bp = (const float*)d_in[8];

    char* ws = (char*)d_ws;
    short* Xb  = (short*)(ws);                 // 8 MB
    short* Wqb = (short*)(ws + (8u  << 20));   // 2 MB each
    short* Wkb = (short*)(ws + (10u << 20));
    short* Wvb = (short*)(ws + (12u << 20));
    short* Wpb = (short*)(ws + (14u << 20));
    short* Qb  = (short*)(ws + (16u << 20));   // 8 MB each
    short* Kb  = (short*)(ws + (24u << 20));
    short* Vtb = (short*)(ws + (32u << 20));   // V transposed per head [B*H*64, T]
    short* Yb  = (short*)(ws + (40u << 20));

    hipLaunchKernelGGL(cvt5, dim3(4096, 5), dim3(256), 0, stream,
                       x, Wq, Wk, Wv, Wp, Xb, Wqb, Wkb, Wvb, Wpb);

    hipLaunchKernelGGL(qkv_gemm, dim3(32, 8, 3), dim3(256), 0, stream,
                       Xb, Wqb, Wkb, Wvb, bq, bk, bv, Qb, Kb, Vtb);

    hipLaunchKernelGGL(attn6, dim3(16, 32), dim3(256), 0, stream, Qb, Kb, Vtb, Yb);

    hipLaunchKernelGGL(proj_gemm, dim3(32, 16), dim3(256), 0, stream, Yb, Wpb, bp, (float*)d_out);
}

// Round 7
// 191.416 us; speedup vs baseline: 1.0822x; 1.0045x over previous
//
#include <hip/hip_runtime.h>
#include <hip/hip_bf16.h>

#define Tsz 2048
#define Csz 1024
#define Hn 16

typedef short s8v __attribute__((ext_vector_type(8)));
typedef short s4v __attribute__((ext_vector_type(4)));
typedef float f4v __attribute__((ext_vector_type(4)));

#define QSCALE (0.125f * 1.44269504088896f)  // 1/sqrt(64) * log2(e), folded into Q

__device__ __forceinline__ short bf_bits(float x) {
    __hip_bfloat16 t = __float2bfloat16(x);
    return *reinterpret_cast<short*>(&t);
}

__device__ __forceinline__ void gload_lds(const void* g, void* l) {
    __builtin_amdgcn_global_load_lds(
        (const __attribute__((address_space(1))) void*)g,
        (__attribute__((address_space(3))) void*)l, 16, 0, 0);
}

// ---------------- fp32 -> bf16 conversion, exact-size grid (8192 blocks) ----------------
__global__ void cvt6(const float* __restrict__ x, const float* __restrict__ wq,
                     const float* __restrict__ wk, const float* __restrict__ wv,
                     const float* __restrict__ wp,
                     short* __restrict__ xo, short* __restrict__ qo,
                     short* __restrict__ ko, short* __restrict__ vo,
                     short* __restrict__ po) {
    const int bx = blockIdx.x;
    const float* in; short* out; int ib;
    if (bx < 4096) { in = x; out = xo; ib = bx; }
    else {
        const int r = bx - 4096, w = r >> 10;
        ib = r & 1023;
        switch (w) {
            case 0: in = wq; out = qo; break;
            case 1: in = wk; out = ko; break;
            case 2: in = wv; out = vo; break;
            default: in = wp; out = po; break;
        }
    }
    const int i = ib * 1024 + threadIdx.x * 4;
    float4 v = *(const float4*)(in + i);
    short4 o;
    o.x = bf_bits(v.x); o.y = bf_bits(v.y); o.z = bf_bits(v.z); o.w = bf_bits(v.w);
    *(short4*)(out + i) = o;
}

// ---------------- fused QKV GEMM (m97 structure) ----------------
// out[m,n] = sum_k X[m,k]*W[n,k] + b[n].  BM=BN=128, BK=32, 256 thr, wave=64x64.
// z=0: Q (bf16, *QSCALE), z=1: K (bf16), z=2: V -> Vt[(b*1024+ch)*T + t] (bf16,
// via LDS-transpose epilogue with coalesced stores).
__global__ __launch_bounds__(256, 3) void qkv_gemm(
    const short* __restrict__ X,
    const short* __restrict__ Wq, const short* __restrict__ Wk, const short* __restrict__ Wv,
    const float* __restrict__ bq, const float* __restrict__ bk, const float* __restrict__ bv,
    short* __restrict__ Qo, short* __restrict__ Ko, short* __restrict__ Vto)
{
    const int z = blockIdx.z;
    const short* W = (z == 0) ? Wq : (z == 1) ? Wk : Wv;
    const float* bias = (z == 0) ? bq : (z == 1) ? bk : bv;

    __shared__ __align__(16) short Ash[128 * 32];
    __shared__ __align__(16) short Bsh[128 * 32];
    __shared__ __align__(16) short TR[64 * 72];   // transpose staging (z==2 epilogue)

    const int tid = threadIdx.x, lane = tid & 63, wave = tid >> 6;
    const int ln = lane & 15, hi = lane >> 4;
    const int m0 = blockIdx.x * 128, n0 = blockIdx.y * 128;
    const int wm = (wave >> 1) * 64, wn = (wave & 1) * 64;

    const short* Ag = X + (size_t)(m0 + (tid >> 2)) * Csz + (tid & 3) * 8;
    const short* Bg = W + (size_t)(n0 + (tid >> 2)) * Csz + (tid & 3) * 8;

    f4v acc[4][4];
    #pragma unroll
    for (int mt = 0; mt < 4; mt++)
        #pragma unroll
        for (int nt = 0; nt < 4; nt++)
            #pragma unroll
            for (int i = 0; i < 4; i++) acc[mt][nt][i] = 0.f;

    for (int k0 = 0; k0 < Csz; k0 += 32) {
        __syncthreads();
        gload_lds(Ag + k0, Ash + tid * 8);
        gload_lds(Ag + k0 + (size_t)64 * Csz, Ash + 2048 + tid * 8);
        gload_lds(Bg + k0, Bsh + tid * 8);
        gload_lds(Bg + k0 + (size_t)64 * Csz, Bsh + 2048 + tid * 8);
        __syncthreads();

        s8v af[4], bfr[4];
        #pragma unroll
        for (int mt = 0; mt < 4; mt++)
            af[mt] = *(const s8v*)(Ash + (wm + mt * 16 + ln) * 32 + hi * 8);
        #pragma unroll
        for (int nt = 0; nt < 4; nt++)
            bfr[nt] = *(const s8v*)(Bsh + (wn + nt * 16 + ln) * 32 + hi * 8);
        #pragma unroll
        for (int mt = 0; mt < 4; mt++)
            #pragma unroll
            for (int nt = 0; nt < 4; nt++)
                acc[mt][nt] = __builtin_amdgcn_mfma_f32_16x16x32_bf16(af[mt], bfr[nt], acc[mt][nt], 0, 0, 0);
    }

    if (z == 2) {
        // LDS-transpose epilogue: 4 passes, each pass covers (m-half, n-half).
        const int b = m0 >> 11, t0 = m0 & 2047;
        float bvv[4];
        #pragma unroll
        for (int nt = 0; nt < 4; nt++) bvv[nt] = bias[n0 + wn + nt * 16 + ln];
        #pragma unroll
        for (int ph = 0; ph < 4; ph++) {
            const int mh = ph >> 1, nh = ph & 1;
            __syncthreads();
            if ((wave >> 1) == mh && (wave & 1) == nh) {
                #pragma unroll
                for (int mt = 0; mt < 4; mt++)
                    #pragma unroll
                    for (int nt = 0; nt < 4; nt++) {
                        s4v pk;
                        #pragma unroll
                        for (int i = 0; i < 4; i++) pk[i] = bf_bits(acc[mt][nt][i] + bvv[nt]);
                        *(s4v*)(TR + (nt * 16 + ln) * 72 + mt * 16 + hi * 4) = pk;
                    }
            }
            __syncthreads();
            const int chl = tid >> 2, seg = tid & 3;   // 64 ch rows x 4 t-segments
            const s8v r0 = *(const s8v*)(TR + chl * 72 + seg * 16);
            const s8v r1 = *(const s8v*)(TR + chl * 72 + seg * 16 + 8);
            short* dst = Vto + (size_t)(b * 1024 + n0 + nh * 64 + chl) * Tsz + t0 + mh * 64 + seg * 16;
            *(s8v*)(dst) = r0;
            *(s8v*)(dst + 8) = r1;
        }
        return;
    }

    const float scale = (z == 0) ? QSCALE : 1.0f;
    short* out = (z == 0) ? Qo : Ko;

    #pragma unroll
    for (int nt = 0; nt < 4; nt++) {
        const int col = n0 + wn + nt * 16 + ln;
        const float bvv = bias[col];
        #pragma unroll
        for (int mt = 0; mt < 4; mt++) {
            const int row0 = m0 + wm + mt * 16 + hi * 4;
            #pragma unroll
            for (int i = 0; i < 4; i++)
                out[(size_t)(row0 + i) * Csz + col] = bf_bits((acc[mt][nt][i] + bvv) * scale);
        }
    }
}

// ---------------- output projection GEMM (f32 out), 128x128 tiles ----------------
__global__ __launch_bounds__(256, 2) void proj_gemm(
    const short* __restrict__ A, const short* __restrict__ W,
    const float* __restrict__ bias, float* __restrict__ out)
{
    __shared__ __align__(16) short Ash[128 * 32];
    __shared__ __align__(16) short Bsh[128 * 32];

    const int tid = threadIdx.x, lane = tid & 63, wave = tid >> 6;
    const int ln = lane & 15, hi = lane >> 4;
    const int m0 = blockIdx.x * 128, n0 = blockIdx.y * 128;
    const int wm = (wave >> 1) * 64, wn = (wave & 1) * 64;

    const short* Ag = A + (size_t)(m0 + (tid >> 2)) * Csz + (tid & 3) * 8;
    const short* Bg = W + (size_t)(n0 + (tid >> 2)) * Csz + (tid & 3) * 8;

    f4v acc[4][4];
    #pragma unroll
    for (int mt = 0; mt < 4; mt++)
        #pragma unroll
        for (int nt = 0; nt < 4; nt++)
            #pragma unroll
            for (int i = 0; i < 4; i++) acc[mt][nt][i] = 0.f;

    for (int k0 = 0; k0 < Csz; k0 += 32) {
        __syncthreads();
        gload_lds(Ag + k0, Ash + tid * 8);
        gload_lds(Ag + k0 + (size_t)64 * Csz, Ash + 2048 + tid * 8);
        gload_lds(Bg + k0, Bsh + tid * 8);
        gload_lds(Bg + k0 + (size_t)64 * Csz, Bsh + 2048 + tid * 8);
        __syncthreads();

        s8v af[4], bfr[4];
        #pragma unroll
        for (int mt = 0; mt < 4; mt++)
            af[mt] = *(const s8v*)(Ash + (wm + mt * 16 + ln) * 32 + hi * 8);
        #pragma unroll
        for (int nt = 0; nt < 4; nt++)
            bfr[nt] = *(const s8v*)(Bsh + (wn + nt * 16 + ln) * 32 + hi * 8);
        #pragma unroll
        for (int mt = 0; mt < 4; mt++)
            #pragma unroll
            for (int nt = 0; nt < 4; nt++)
                acc[mt][nt] = __builtin_amdgcn_mfma_f32_16x16x32_bf16(af[mt], bfr[nt], acc[mt][nt], 0, 0, 0);
    }

    #pragma unroll
    for (int nt = 0; nt < 4; nt++) {
        const int col = n0 + wn + nt * 16 + ln;
        const float bvv = bias[col];
        #pragma unroll
        for (int mt = 0; mt < 4; mt++)
            #pragma unroll
            for (int i = 0; i < 4; i++)
                out[(size_t)(m0 + wm + mt * 16 + hi * 4 + i) * Csz + col] = acc[mt][nt][i] + bvv;
    }
}

// ---------------- Flash attention v7 (8 waves, shared staging, dbuf, 1 barrier/iter) ----
// Q,K: [B,T,C] bf16; Vt: [B*H*64, T] bf16; Y: [B,T,C] bf16.
// St = K*Q^T, O^T = Vt*P^T; P^T re-laid out via wave-private LDS.
// Block: 512 thr = 8 waves = 2 groups; group 0 handles q-tiles {p, 31-p},
// group 1 handles {15-p, 16+p} (p = blockIdx.x in 0..7); staging shared by both.
// K/V LDS double-buffered: one __syncthreads per key-tile iteration.
__global__ __launch_bounds__(512, 2) void attn7(
    const short* __restrict__ Q, const short* __restrict__ Kg,
    const short* __restrict__ Vt, short* __restrict__ Y)
{
    __shared__ __align__(16) short Ksh[2][64 * 72];  // [buf][key][d], pitch 72
    __shared__ __align__(16) short Vsh[2][64 * 72];  // [buf][d][key], pitch 72
    __shared__ __align__(16) short Psh[8][16 * 72];  // per-wave Pq[q][key]

    const int tid = threadIdx.x, lane = tid & 63, wave = tid >> 6;
    const int wv = wave & 3, g = wave >> 2;
    const int ln = lane & 15, hi = lane >> 4;
    const int p = blockIdx.x;                 // 0..7
    const int qts[2] = { g ? 15 - p : p, g ? 16 + p : 31 - p };  // light, heavy
    const int bh = blockIdx.y;
    const size_t base = (size_t)(bh >> 4) * Tsz * Csz + (size_t)(bh & 15) * 64;
    const size_t vtbase = (size_t)bh * 64 * Tsz;
    const int qrel = wv * 16 + ln;            // within-tile q row (MFMA n-col)
    short* Pq = Psh[wave];

    s8v qf[2][2];
    #pragma unroll
    for (int t = 0; t < 2; t++)
        #pragma unroll
        for (int kk = 0; kk < 2; kk++)
            qf[t][kk] = *(const s8v*)(Q + base + (size_t)(qts[t] * 64 + qrel) * Csz + kk * 32 + hi * 8);

    f4v o[2][4];
    float lsum[2] = {0.f, 0.f};
    #pragma unroll
    for (int t = 0; t < 2; t++)
        #pragma unroll
        for (int dt = 0; dt < 4; dt++)
            #pragma unroll
            for (int i = 0; i < 4; i++) o[t][dt][i] = 0.f;

    // staging: 512 threads, each 16 B of K and 16 B of V per tile
    const int sr = tid >> 3, sc = (tid & 7) * 8;
    const short* Kp = Kg + base + (size_t)sr * Csz + sc;
    const short* Vp = Vt + vtbase + (size_t)sr * Tsz + sc;
    const int swo = sr * 72 + sc;

    const int nkb = 32 - p;                   // covers both groups' needs

    // prologue: tile0 -> buf0; prefetch tile1 into regs
    s8v kR = *(const s8v*)(Kp);
    s8v vR = *(const s8v*)(Vp);
    *(s8v*)(&Ksh[0][swo]) = kR;
    *(s8v*)(&Vsh[0][swo]) = vR;
    kR = *(const s8v*)(Kp + (size_t)64 * Csz);
    vR = *(const s8v*)(Vp + 64);
    __syncthreads();

    for (int kb = 0; kb < nkb; kb++) {
        const int buf = kb & 1;
        if (kb + 1 < nkb) {
            // stage tile kb+1 into the other buffer; prefetch tile kb+2
            *(s8v*)(&Ksh[buf ^ 1][swo]) = kR;
            *(s8v*)(&Vsh[buf ^ 1][swo]) = vR;
            const int knx = (kb + 2 < nkb) ? (kb + 2) * 64 : (nkb - 1) * 64;
            kR = *(const s8v*)(Kp + (size_t)knx * Csz);
            vR = *(const s8v*)(Vp + knx);
        }

        s8v kf[2][4], vf[2][4];
        #pragma unroll
        for (int nt = 0; nt < 4; nt++)
            #pragma unroll
            for (int kk = 0; kk < 2; kk++) {
                kf[kk][nt] = *(const s8v*)(&Ksh[buf][(nt * 16 + ln) * 72 + kk * 32 + hi * 8]);
                vf[kk][nt] = *(const s8v*)(&Vsh[buf][(nt * 16 + ln) * 72 + kk * 32 + hi * 8]);
            }

        #pragma unroll
        for (int t = 0; t < 2; t++) {
            if (kb > qts[t]) continue;         // wave-uniform
            const bool dg = (kb == qts[t]);    // diagonal block for this tile

            f4v s[4];
            #pragma unroll
            for (int nt = 0; nt < 4; nt++) {
                #pragma unroll
                for (int i = 0; i < 4; i++) s[nt][i] = 0.f;
                s[nt] = __builtin_amdgcn_mfma_f32_16x16x32_bf16(kf[0][nt], qf[t][0], s[nt], 0, 0, 0);
                s[nt] = __builtin_amdgcn_mfma_f32_16x16x32_bf16(kf[1][nt], qf[t][1], s[nt], 0, 0, 0);
            }

            // P^T write: lane holds keys nt*16+hi*4+{0..3} for q=ln; l accumulated in VALU
            #pragma unroll
            for (int nt = 0; nt < 4; nt++) {
                float pv[4];
                #pragma unroll
                for (int i = 0; i < 4; i++) pv[i] = exp2f(s[nt][i]);
                if (dg) {
                    const int kr = nt * 16 + hi * 4;
                    #pragma unroll
                    for (int i = 0; i < 4; i++)
                        if (kr + i > qrel) pv[i] = 0.f;
                }
                lsum[t] += (pv[0] + pv[1]) + (pv[2] + pv[3]);
                s4v w;
                #pragma unroll
                for (int i = 0; i < 4; i++) w[i] = bf_bits(pv[i]);
                *(s4v*)(Pq + ln * 72 + nt * 16 + hi * 4) = w;  // ds_write_b64
            }
            // B-frag read: keys kk*32+hi*8+{0..7} for q=ln
            const s8v pb0 = *(const s8v*)(Pq + ln * 72 + hi * 8);
            const s8v pb1 = *(const s8v*)(Pq + ln * 72 + 32 + hi * 8);

            #pragma unroll
            for (int dt = 0; dt < 4; dt++) {
                o[t][dt] = __builtin_amdgcn_mfma_f32_16x16x32_bf16(vf[0][dt], pb0, o[t][dt], 0, 0, 0);
                o[t][dt] = __builtin_amdgcn_mfma_f32_16x16x32_bf16(vf[1][dt], pb1, o[t][dt], 0, 0, 0);
            }
        }
        __syncthreads();
    }

    // l = sum over all keys for q=ln: reduce across the 4 hi-groups (lanes ln+16k)
    #pragma unroll
    for (int t = 0; t < 2; t++) {
        float l = lsum[t];
        l += __shfl_xor(l, 16);
        l += __shfl_xor(l, 32);
        const float inv = 1.0f / l;
        const int qrow = qts[t] * 64 + qrel;
        #pragma unroll
        for (int dt = 0; dt < 4; dt++) {
            s4v w;
            #pragma unroll
            for (int i = 0; i < 4; i++) w[i] = bf_bits(o[t][dt][i] * inv);
            *(s4v*)(Y + base + (size_t)qrow * Csz + dt * 16 + hi * 4) = w;
        }
    }
}

extern "C" void kernel_launch(void* const* d_in, const int* in_sizes, int n_in,
                              void* d_out, int out_size, void* d_ws, size_t ws_size,
                              hipStream_t stream) {
    const float* x  = (const float*)d_in[0];
    const float* Wq = (const float*)d_in[1];
    const float* bq = (const float*)d_in[2];
    const float* Wk = (const float*)d_in[3];
    const float* bk = (const float*)d_in[4];
    const float* Wv = (const float*)d_in[5];
    const float* bv = (const float*)d_in[6];
    const float* Wp = (const float*)d_in[7];
    const float* bp = (const float*)d_in[8];

    char* ws = (char*)d_ws;
    short* Xb  = (short*)(ws);                 // 8 MB
    short* Wqb = (short*)(ws + (8u  << 20));   // 2 MB each
    short* Wkb = (short*)(ws + (10u << 20));
    short* Wvb = (short*)(ws + (12u << 20));
    short* Wpb = (short*)(ws + (14u << 20));
    short* Qb  = (short*)(ws + (16u << 20));   // 8 MB each
    short* Kb  = (short*)(ws + (24u << 20));
    short* Vtb = (short*)(ws + (32u << 20));   // V transposed per head [B*H*64, T]
    short* Yb  = (short*)(ws + (40u << 20));

    hipLaunchKernelGGL(cvt6, dim3(8192), dim3(256), 0, stream,
                       x, Wq, Wk, Wv, Wp, Xb, Wqb, Wkb, Wvb, Wpb);

    hipLaunchKernelGGL(qkv_gemm, dim3(32, 8, 3), dim3(256), 0, stream,
                       Xb, Wqb, Wkb, Wvb, bq, bk, bv, Qb, Kb, Vtb);

    hipLaunchKernelGGL(attn7, dim3(8, 32), dim3(512), 0, stream, Qb, Kb, Vtb, Yb);

    hipLaunchKernelGGL(proj_gemm, dim3(32, 8), dim3(256), 0, stream, Yb, Wpb, bp, (float*)d_out);
}